// Round 13
// baseline (315.772 us; speedup 1.0000x reference)
//
#include <hip/hip_runtime.h>
#include <hip/hip_bf16.h>
#include <cstdint>

#define B_N 16384
#define KN 64
#define DN 256
#define AN 64
#define ROWS 4

typedef float f32x4 __attribute__((ext_vector_type(4)));
typedef float f32x2 __attribute__((ext_vector_type(2)));
typedef short s16x8 __attribute__((ext_vector_type(8)));

// pack two f32 -> one u32 of 2x bf16 (RTN); .x lands in low 16 bits
static __device__ inline unsigned int pk2(float a, float b) {
    __hip_bfloat162 h = __float22bfloat162_rn(make_float2(a, b));
    return *reinterpret_cast<unsigned int*>(&h);
}
static __device__ inline float bf_lo(unsigned int v) { return __uint_as_float(v << 16); }
static __device__ inline float bf_hi(unsigned int v) { return __uint_as_float(v & 0xFFFF0000u); }

// ---------------------------------------------------------------------------
// K0: M = Wq^T @ Wk (256x256 f32)  and  Wgb = bf16(Wgate) ([256 out][512 in])
// ---------------------------------------------------------------------------
__global__ __launch_bounds__(256) void prep_kernel(const float* __restrict__ Wq,
                                                   const float* __restrict__ Wk,
                                                   const float* __restrict__ Wgate,
                                                   float* __restrict__ M,
                                                   unsigned int* __restrict__ Wgb) {
    int blk = blockIdx.x;
    int t = threadIdx.x;
    if (blk < DN) {
        float acc = 0.f;
        #pragma unroll
        for (int a = 0; a < AN; ++a)
            acc += Wq[a * DN + blk] * Wk[a * DN + t];
        M[blk * DN + t] = acc;
    } else {
        int d = blk - DN;                    // 0..255 output row
        const float* src = Wgate + (size_t)d * (2 * DN);
        Wgb[(size_t)d * 256 + t] = pk2(src[2 * t], src[2 * t + 1]);
    }
}

// ---------------------------------------------------------------------------
// K0b: qk = center @ M, output bf16 pairs [B][128 words] (8 MB).
// M fully L2-resident here (no competing stream). R2-verified tile.
// ---------------------------------------------------------------------------
__global__ __launch_bounds__(256) void qk_kernel(const float* __restrict__ center,
                                                 const float* __restrict__ M,
                                                 unsigned int* __restrict__ qkb) {
    __shared__ float xs[32 * DN];            // 32 KB
    int r0 = blockIdx.x * 32;
    int tid = threadIdx.x;

    const float4* src = (const float4*)(center + (size_t)r0 * DN);
    float4* dst = (float4*)xs;
    #pragma unroll
    for (int i = 0; i < 8; ++i)
        dst[tid + 256 * i] = src[tid + 256 * i];
    __syncthreads();

    int ty = tid >> 5, tx = tid & 31;
    float acc[4][8];
    #pragma unroll
    for (int r = 0; r < 4; ++r)
        #pragma unroll
        for (int c = 0; c < 8; ++c) acc[r][c] = 0.f;

    for (int k4 = 0; k4 < DN; k4 += 4) {
        float4 xr[4];
        #pragma unroll
        for (int r = 0; r < 4; ++r)
            xr[r] = *(const float4*)(&xs[(ty * 4 + r) * DN + k4]);
        #pragma unroll
        for (int kk = 0; kk < 4; ++kk) {
            float4 ma = *(const float4*)(&M[(size_t)(k4 + kk) * DN + tx * 8]);
            float4 mb = *(const float4*)(&M[(size_t)(k4 + kk) * DN + tx * 8 + 4]);
            #pragma unroll
            for (int r = 0; r < 4; ++r) {
                float x = (&xr[r].x)[kk];
                acc[r][0] += x * ma.x; acc[r][1] += x * ma.y;
                acc[r][2] += x * ma.z; acc[r][3] += x * ma.w;
                acc[r][4] += x * mb.x; acc[r][5] += x * mb.y;
                acc[r][6] += x * mb.z; acc[r][7] += x * mb.w;
            }
        }
    }
    #pragma unroll
    for (int r = 0; r < 4; ++r) {
        size_t row = (size_t)(r0 + ty * 4 + r);
        uint4 o;
        o.x = pk2(acc[r][0], acc[r][1]);
        o.y = pk2(acc[r][2], acc[r][3]);
        o.z = pk2(acc[r][4], acc[r][5]);
        o.w = pk2(acc[r][6], acc[r][7]);
        *(uint4*)&qkb[row * 128 + tx * 4] = o;
    }
}

// ---------------------------------------------------------------------------
// K1: fused attention + gate. 4096 blocks x 4 rows, ~47 KB LDS,
// launch_bounds(256,2) (verified regime). Row loop = R12's verified
// structure, but ctx -> sctx (LDS, never HBM). Then the R7-verified MFMA
// gate runs in-block (A = 4 rows [cen|ctx] bf16, rows mod-4 duplicated to
// fill the 16-row fragment, dup outputs discarded; B = Wgb from L2),
// f32 sigmoid blend from scen/sctx, direct out store. Gate lands in the
// last-row no-prefetch tail; Wgb is L2-resident (512 KB/XCD).
// ---------------------------------------------------------------------------
__global__ __launch_bounds__(256, 2) void attn_gate_kernel(const float* __restrict__ neigh,
                                                           const unsigned int* __restrict__ qkb,
                                                           const float* __restrict__ ppi,
                                                           const float* __restrict__ center,
                                                           const unsigned int* __restrict__ Wgb,
                                                           const float* __restrict__ bgate,
                                                           float* __restrict__ out) {
    __shared__ unsigned int sn[KN * 128];    // 32 KB current tile (bf16 pairs)
    __shared__ unsigned int sqk[ROWS * 128]; //  2 KB q rows (bf16 pairs)
    __shared__ float slog[KN];               // 256 B logits
    __shared__ float sattn[4][KN];           //  1 KB per-wave attn copies
    __shared__ float scen[ROWS * DN];        //  4 KB center rows (f32)
    __shared__ float sctx[ROWS * DN];        //  4 KB context rows (f32)
    __shared__ unsigned int sgt[ROWS * 260]; //  4 KB A-matrix bf16 pairs [row][260]

    const int tid = threadIdx.x;
    const int lane = tid & 63;
    const int wv = tid >> 6;
    const int b0 = blockIdx.x * ROWS;

    // issue row-0 tile prefetch (nontemporal: one-touch stream)
    f32x4 rr[16];
    {
        const f32x4* t4 = (const f32x4*)(neigh + (size_t)b0 * (KN * DN));
        #pragma unroll
        for (int i = 0; i < 16; ++i)
            rr[i] = __builtin_nontemporal_load(t4 + tid + 256 * i);
    }

    // qk rows -> LDS; center rows -> LDS (f32)
    ((uint2*)sqk)[tid] = ((const uint2*)(qkb + (size_t)b0 * 128))[tid];
    ((float4*)scen)[tid] = ((const float4*)(center + (size_t)b0 * DN))[tid];

    // ppi rows -> registers (every wave keeps a copy; lane k holds ppi[k])
    float pv[ROWS];
    #pragma unroll
    for (int r = 0; r < ROWS; ++r) pv[r] = ppi[(size_t)(b0 + r) * KN + lane];

    #pragma unroll
    for (int r = 0; r < ROWS; ++r) {
        if (r > 0) __syncthreads();          // guard: prev row's ctx reads of sn done

        // staged regs -> sn (bf16 pairs)
        {
            uint2* dst = (uint2*)sn;
            #pragma unroll
            for (int i = 0; i < 16; ++i)
                dst[tid + 256 * i] = make_uint2(pk2(rr[i].x, rr[i].y), pk2(rr[i].z, rr[i].w));
        }
        // prefetch next row's tile (in flight during this row's compute)
        if (r < ROWS - 1) {
            const f32x4* n4 = (const f32x4*)(neigh + (size_t)(b0 + r + 1) * (KN * DN));
            #pragma unroll
            for (int i = 0; i < 16; ++i)
                rr[i] = __builtin_nontemporal_load(n4 + tid + 256 * i);
        }
        __syncthreads();                      // B1: sn (and for r=0: sqk) visible

        // logits: group g=tid>>2 owns k-row g; rotated d-walk (2-way banks)
        {
            const int g = tid >> 2, j = tid & 3;
            float acc = 0.f;
            #pragma unroll
            for (int m = 0; m < 32; ++m) {
                int s = (m + g) & 31;
                int p = j + 4 * s;            // pair index 0..127
                unsigned int nv = sn[g * 128 + p];
                unsigned int qv = sqk[r * 128 + p];
                acc += bf_lo(nv) * bf_lo(qv) + bf_hi(nv) * bf_hi(qv);
            }
            acc += __shfl_xor(acc, 1, 64);
            acc += __shfl_xor(acc, 2, 64);
            if (j == 0) slog[g] = acc;
        }
        __syncthreads();                      // B2: slog visible

        // softmax + ppi renorm: every wave redundantly; own sattn copy
        {
            float l = slog[lane] * 0.125f;    // scale = 64^-0.5
            float mx = l;
            #pragma unroll
            for (int off = 32; off >= 1; off >>= 1)
                mx = fmaxf(mx, __shfl_xor(mx, off, 64));
            float e = expf(l - mx);
            float se = e;
            #pragma unroll
            for (int off = 32; off >= 1; off >>= 1)
                se += __shfl_xor(se, off, 64);
            float t = (e / se) * pv[r];
            float st = t;
            #pragma unroll
            for (int off = 32; off >= 1; off >>= 1)
                st += __shfl_xor(st, off, 64);
            sattn[wv][lane] = t / (st + 1e-8f);
        }

        // ctx: one d per thread -> sctx (LDS only, never HBM)
        {
            const int w = tid >> 1;
            const int sh = (tid & 1) ? 0 : 16;
            float c = 0.f;
            #pragma unroll
            for (int k = 0; k < KN; ++k) {
                unsigned int nv = sn[k * 128 + w];
                float xv = __uint_as_float((nv << sh) & 0xFFFF0000u);
                c += sattn[wv][k] * xv;
            }
            sctx[r * DN + tid] = c;
        }
    }
    __syncthreads();                          // sctx complete

    // ---- build A-matrix: sgt[row][pair p] = bf16([cen(128w) | ctx(128w)]) ----
    #pragma unroll
    for (int i = 0; i < 4; ++i) {
        int w = tid + 256 * i;                // 0..1023
        int row = w >> 8, p = w & 255;
        const float* srcrow = (p < 128) ? &scen[row * DN] : &sctx[row * DN];
        int pp = (p & 127) * 2;
        sgt[row * 260 + p] = pk2(srcrow[pp], srcrow[pp + 1]);
    }
    __syncthreads();                          // sgt visible

    // ---- gate GEMM via MFMA (R7-verified layout) + blend + store ----
    {
        const int l15 = lane & 15, lhi = lane >> 4;
        const int row4 = l15 & 3;             // rows duplicated mod 4

        f32x4 acc[4];
        #pragma unroll
        for (int nt = 0; nt < 4; ++nt) acc[nt] = (f32x4){0.f, 0.f, 0.f, 0.f};

        #pragma unroll
        for (int ks = 0; ks < 16; ++ks) {     // K = 512 bf16, 32 per step
            s16x8 a = *(const s16x8*)&sgt[row4 * 260 + ks * 16 + lhi * 4];
            #pragma unroll
            for (int nt = 0; nt < 4; ++nt) {
                int d = wv * 64 + nt * 16 + l15;
                s16x8 b = *(const s16x8*)&Wgb[(size_t)d * 256 + ks * 16 + lhi * 4];
                acc[nt] = __builtin_amdgcn_mfma_f32_16x16x32_bf16(a, b, acc[nt], 0, 0, 0);
            }
        }

        // valid outputs: D row = lhi*4+reg in 0..3  <=>  lhi==0 (lanes 0..15)
        if (lhi == 0) {
            #pragma unroll
            for (int nt = 0; nt < 4; ++nt) {
                int col = wv * 64 + nt * 16 + l15;
                float bg = bgate[col];
                #pragma unroll
                for (int reg = 0; reg < 4; ++reg) {
                    int row = reg;            // rows 0..3
                    float z = acc[nt][reg] + bg;
                    float gt = 1.0f / (1.0f + expf(-z));
                    float ce = scen[row * DN + col];
                    float cx = sctx[row * DN + col];
                    out[(size_t)(b0 + row) * DN + col] = gt * ce + (1.0f - gt) * cx;
                }
            }
        }
    }
}

// ---------------------------------------------------------------------------
extern "C" void kernel_launch(void* const* d_in, const int* in_sizes, int n_in,
                              void* d_out, int out_size, void* d_ws, size_t ws_size,
                              hipStream_t stream) {
    const float* center = (const float*)d_in[0];
    const float* neigh  = (const float*)d_in[1];
    const float* ppi    = (const float*)d_in[2];
    const float* Wq     = (const float*)d_in[3];
    const float* Wk     = (const float*)d_in[4];
    const float* Wgate  = (const float*)d_in[5];
    const float* bgate  = (const float*)d_in[6];
    float* out = (float*)d_out;

    char* ws = (char*)d_ws;
    float* M          = (float*)(ws);                            // 256 KB
    unsigned int* Wgb = (unsigned int*)(ws + 262144);            // 256 KB
    unsigned int* qkb = (unsigned int*)(ws + 524288);            // 8 MB bf16 pairs

    prep_kernel<<<dim3(512), dim3(256), 0, stream>>>(Wq, Wk, Wgate, M, Wgb);
    qk_kernel<<<dim3(B_N / 32), dim3(256), 0, stream>>>(center, M, qkb);
    attn_gate_kernel<<<dim3(B_N / ROWS), dim3(256), 0, stream>>>(neigh, qkb, ppi,
                                                                 center, Wgb, bgate, out);
}

// Round 14
// 285.668 us; speedup vs baseline: 1.1054x; 1.1054x over previous
//
#include <hip/hip_runtime.h>
#include <hip/hip_bf16.h>
#include <cstdint>

#define B_N 16384
#define KN 64
#define DN 256
#define AN 64
#define ROWS 4

typedef float f32x4 __attribute__((ext_vector_type(4)));
typedef short s16x8 __attribute__((ext_vector_type(8)));

// pack two f32 -> one u32 of 2x bf16 (RTN); .x lands in low 16 bits
static __device__ inline unsigned int pk2(float a, float b) {
    __hip_bfloat162 h = __float22bfloat162_rn(make_float2(a, b));
    return *reinterpret_cast<unsigned int*>(&h);
}
static __device__ inline float bf_lo(unsigned int v) { return __uint_as_float(v << 16); }
static __device__ inline float bf_hi(unsigned int v) { return __uint_as_float(v & 0xFFFF0000u); }

// ---------------------------------------------------------------------------
// K0: M = Wq^T @ Wk (256x256 f32)  and  Wgb = bf16(Wgate) ([256 out][512 in])
// ---------------------------------------------------------------------------
__global__ __launch_bounds__(256) void prep_kernel(const float* __restrict__ Wq,
                                                   const float* __restrict__ Wk,
                                                   const float* __restrict__ Wgate,
                                                   float* __restrict__ M,
                                                   unsigned int* __restrict__ Wgb) {
    int blk = blockIdx.x;
    int t = threadIdx.x;
    if (blk < DN) {
        float acc = 0.f;
        #pragma unroll
        for (int a = 0; a < AN; ++a)
            acc += Wq[a * DN + blk] * Wk[a * DN + t];
        M[blk * DN + t] = acc;
    } else {
        int d = blk - DN;                    // 0..255 output row
        const float* src = Wgate + (size_t)d * (2 * DN);
        Wgb[(size_t)d * 256 + t] = pk2(src[2 * t], src[2 * t + 1]);
    }
}

// ---------------------------------------------------------------------------
// K0b: qk = center @ M, output bf16 pairs [B][128 words] (8 MB).
// M fully L2-resident here (no competing stream). R2-verified tile.
// ---------------------------------------------------------------------------
__global__ __launch_bounds__(256) void qk_kernel(const float* __restrict__ center,
                                                 const float* __restrict__ M,
                                                 unsigned int* __restrict__ qkb) {
    __shared__ float xs[32 * DN];            // 32 KB
    int r0 = blockIdx.x * 32;
    int tid = threadIdx.x;

    const float4* src = (const float4*)(center + (size_t)r0 * DN);
    float4* dst = (float4*)xs;
    #pragma unroll
    for (int i = 0; i < 8; ++i)
        dst[tid + 256 * i] = src[tid + 256 * i];
    __syncthreads();

    int ty = tid >> 5, tx = tid & 31;
    float acc[4][8];
    #pragma unroll
    for (int r = 0; r < 4; ++r)
        #pragma unroll
        for (int c = 0; c < 8; ++c) acc[r][c] = 0.f;

    for (int k4 = 0; k4 < DN; k4 += 4) {
        float4 xr[4];
        #pragma unroll
        for (int r = 0; r < 4; ++r)
            xr[r] = *(const float4*)(&xs[(ty * 4 + r) * DN + k4]);
        #pragma unroll
        for (int kk = 0; kk < 4; ++kk) {
            float4 ma = *(const float4*)(&M[(size_t)(k4 + kk) * DN + tx * 8]);
            float4 mb = *(const float4*)(&M[(size_t)(k4 + kk) * DN + tx * 8 + 4]);
            #pragma unroll
            for (int r = 0; r < 4; ++r) {
                float x = (&xr[r].x)[kk];
                acc[r][0] += x * ma.x; acc[r][1] += x * ma.y;
                acc[r][2] += x * ma.z; acc[r][3] += x * ma.w;
                acc[r][4] += x * mb.x; acc[r][5] += x * mb.y;
                acc[r][6] += x * mb.z; acc[r][7] += x * mb.w;
            }
        }
    }
    #pragma unroll
    for (int r = 0; r < 4; ++r) {
        size_t row = (size_t)(r0 + ty * 4 + r);
        uint4 o;
        o.x = pk2(acc[r][0], acc[r][1]);
        o.y = pk2(acc[r][2], acc[r][3]);
        o.z = pk2(acc[r][4], acc[r][5]);
        o.w = pk2(acc[r][6], acc[r][7]);
        *(uint4*)&qkb[row * 128 + tx * 4] = o;
    }
}

// ---------------------------------------------------------------------------
// K1: attention. 4096 blocks x 4 rows, ~35.3 KB LDS. Half-row prefetch
// (rr[8] = 32 VGPRs) keeps register footprint under the (256,4) cap ->
// 4 blocks/CU, 16 waves: staggered blocks cover each other's load waits.
// Compute phases (logits/softmax/ctx) identical to R12's verified code.
// ---------------------------------------------------------------------------
__global__ __launch_bounds__(256, 4) void attn_kernel(const float* __restrict__ neigh,
                                                      const unsigned int* __restrict__ qkb,
                                                      const float* __restrict__ ppi,
                                                      float* __restrict__ ctx) {
    __shared__ unsigned int sn[KN * 128];    // 32 KB current tile (bf16 pairs)
    __shared__ unsigned int sqk[ROWS * 128]; //  2 KB q rows (bf16 pairs)
    __shared__ float slog[KN];               // 256 B logits
    __shared__ float sattn[4][KN];           //  1 KB per-wave attn copies

    const int tid = threadIdx.x;
    const int lane = tid & 63;
    const int wv = tid >> 6;
    const int b0 = blockIdx.x * ROWS;

    // prologue: issue row-0 half0 (k 0..31) prefetch
    f32x4 rr[8];
    {
        const f32x4* t4 = (const f32x4*)(neigh + (size_t)b0 * (KN * DN));
        #pragma unroll
        for (int i = 0; i < 8; ++i)
            rr[i] = __builtin_nontemporal_load(t4 + tid + 256 * i);
    }

    // qk rows -> LDS (512 words); ppi -> regs (hides under prologue loads)
    ((uint2*)sqk)[tid] = ((const uint2*)(qkb + (size_t)b0 * 128))[tid];
    float pv[ROWS];
    #pragma unroll
    for (int r = 0; r < ROWS; ++r) pv[r] = ppi[(size_t)(b0 + r) * KN + lane];

    #pragma unroll
    for (int r = 0; r < ROWS; ++r) {
        if (r > 0) __syncthreads();          // guard: prev row's ctx reads of sn done

        const f32x4* row4 = (const f32x4*)(neigh + (size_t)(b0 + r) * (KN * DN));

        // stage half0 (rr holds it), issue half1
        {
            uint2* dst = (uint2*)sn;
            #pragma unroll
            for (int i = 0; i < 8; ++i)
                dst[tid + 256 * i] = make_uint2(pk2(rr[i].x, rr[i].y), pk2(rr[i].z, rr[i].w));
            #pragma unroll
            for (int i = 0; i < 8; ++i)
                rr[i] = __builtin_nontemporal_load(row4 + 2048 + tid + 256 * i);
            // stage half1 (waitcnt inserted by compiler)
            #pragma unroll
            for (int i = 0; i < 8; ++i)
                dst[2048 + tid + 256 * i] = make_uint2(pk2(rr[i].x, rr[i].y), pk2(rr[i].z, rr[i].w));
        }
        // issue next row's half0 (in flight during this row's compute)
        if (r < ROWS - 1) {
            const f32x4* n4 = (const f32x4*)(neigh + (size_t)(b0 + r + 1) * (KN * DN));
            #pragma unroll
            for (int i = 0; i < 8; ++i)
                rr[i] = __builtin_nontemporal_load(n4 + tid + 256 * i);
        }
        __syncthreads();                      // B1: sn (and for r=0: sqk) visible

        // logits: group g=tid>>2 owns k-row g; rotated d-walk (2-way banks)
        {
            const int g = tid >> 2, j = tid & 3;
            float acc = 0.f;
            #pragma unroll
            for (int m = 0; m < 32; ++m) {
                int s = (m + g) & 31;
                int p = j + 4 * s;            // pair index 0..127
                unsigned int nv = sn[g * 128 + p];
                unsigned int qv = sqk[r * 128 + p];
                acc += bf_lo(nv) * bf_lo(qv) + bf_hi(nv) * bf_hi(qv);
            }
            acc += __shfl_xor(acc, 1, 64);
            acc += __shfl_xor(acc, 2, 64);
            if (j == 0) slog[g] = acc;
        }
        __syncthreads();                      // B2: slog visible

        // softmax + ppi renorm: every wave redundantly; own sattn copy
        {
            float l = slog[lane] * 0.125f;    // scale = 64^-0.5
            float mx = l;
            #pragma unroll
            for (int off = 32; off >= 1; off >>= 1)
                mx = fmaxf(mx, __shfl_xor(mx, off, 64));
            float e = expf(l - mx);
            float se = e;
            #pragma unroll
            for (int off = 32; off >= 1; off >>= 1)
                se += __shfl_xor(se, off, 64);
            float t = (e / se) * pv[r];
            float st = t;
            #pragma unroll
            for (int off = 32; off >= 1; off >>= 1)
                st += __shfl_xor(st, off, 64);
            sattn[wv][lane] = t / (st + 1e-8f);
        }

        // ctx: one d per thread; adjacent lanes share each sn word
        {
            const int w = tid >> 1;
            const int sh = (tid & 1) ? 0 : 16;
            float c = 0.f;
            #pragma unroll
            for (int k = 0; k < KN; ++k) {
                unsigned int nv = sn[k * 128 + w];
                float xv = __uint_as_float((nv << sh) & 0xFFFF0000u);
                c += sattn[wv][k] * xv;
            }
            __builtin_nontemporal_store(c, ctx + (size_t)(b0 + r) * DN + tid);
        }
    }
}

// ---------------------------------------------------------------------------
// K2: gate GEMM via MFMA bf16 + sigmoid blend (R7-verified, 32 rows/block).
// ---------------------------------------------------------------------------
__global__ __launch_bounds__(256) void gate_kernel(const float* __restrict__ center,
                                                   const float* __restrict__ ctxw,
                                                   const unsigned int* __restrict__ Wgb,
                                                   const float* __restrict__ bgate,
                                                   float* __restrict__ out) {
    __shared__ unsigned int xsb[32 * 260];   // 33.3 KB bf16 pairs: [cen 128 | ctx 128 | pad 4]
    const int r0 = blockIdx.x * 32;
    const int tid = threadIdx.x;

    const float4* c4 = (const float4*)(center + (size_t)r0 * DN);
    const float4* x4 = (const float4*)(ctxw + (size_t)r0 * DN);
    #pragma unroll
    for (int i = 0; i < 8; ++i) {
        int idx = tid + 256 * i;             // 0..2047
        int r = idx >> 6, c = idx & 63;
        float4 cv = c4[idx];
        float4 xv = x4[idx];
        *(uint2*)&xsb[r * 260 + 2 * c]       = make_uint2(pk2(cv.x, cv.y), pk2(cv.z, cv.w));
        *(uint2*)&xsb[r * 260 + 128 + 2 * c] = make_uint2(pk2(xv.x, xv.y), pk2(xv.z, xv.w));
    }
    __syncthreads();

    const int wave = tid >> 6, lane = tid & 63;
    const int l15 = lane & 15, lhi = lane >> 4;

    f32x4 acc[2][4];
    #pragma unroll
    for (int mt = 0; mt < 2; ++mt)
        #pragma unroll
        for (int nt = 0; nt < 4; ++nt)
            acc[mt][nt] = (f32x4){0.f, 0.f, 0.f, 0.f};

    #pragma unroll
    for (int ks = 0; ks < 16; ++ks) {        // K = 512 bf16, 32 per step
        s16x8 a0 = *(const s16x8*)&xsb[(l15)      * 260 + ks * 16 + lhi * 4];
        s16x8 a1 = *(const s16x8*)&xsb[(l15 + 16) * 260 + ks * 16 + lhi * 4];
        s16x8 b[4];
        #pragma unroll
        for (int nt = 0; nt < 4; ++nt) {
            int d = wave * 64 + nt * 16 + l15;
            b[nt] = *(const s16x8*)&Wgb[(size_t)d * 256 + ks * 16 + lhi * 4];
        }
        #pragma unroll
        for (int nt = 0; nt < 4; ++nt) {
            acc[0][nt] = __builtin_amdgcn_mfma_f32_16x16x32_bf16(a0, b[nt], acc[0][nt], 0, 0, 0);
            acc[1][nt] = __builtin_amdgcn_mfma_f32_16x16x32_bf16(a1, b[nt], acc[1][nt], 0, 0, 0);
        }
    }

    #pragma unroll
    for (int mt = 0; mt < 2; ++mt)
        #pragma unroll
        for (int nt = 0; nt < 4; ++nt) {
            int col = wave * 64 + nt * 16 + l15;
            float bg = bgate[col];
            #pragma unroll
            for (int reg = 0; reg < 4; ++reg) {
                int row = mt * 16 + lhi * 4 + reg;
                size_t gr = (size_t)(r0 + row);
                float z = acc[mt][nt][reg] + bg;
                float gt = 1.0f / (1.0f + expf(-z));
                float ce = center[gr * DN + col];   // f32, L2-warm
                float cx = ctxw[gr * DN + col];     // f32, L2-warm
                out[gr * DN + col] = gt * ce + (1.0f - gt) * cx;
            }
        }
}

// ---------------------------------------------------------------------------
extern "C" void kernel_launch(void* const* d_in, const int* in_sizes, int n_in,
                              void* d_out, int out_size, void* d_ws, size_t ws_size,
                              hipStream_t stream) {
    const float* center = (const float*)d_in[0];
    const float* neigh  = (const float*)d_in[1];
    const float* ppi    = (const float*)d_in[2];
    const float* Wq     = (const float*)d_in[3];
    const float* Wk     = (const float*)d_in[4];
    const float* Wgate  = (const float*)d_in[5];
    const float* bgate  = (const float*)d_in[6];
    float* out = (float*)d_out;

    char* ws = (char*)d_ws;
    float* M          = (float*)(ws);                            // 256 KB
    unsigned int* Wgb = (unsigned int*)(ws + 262144);            // 256 KB
    unsigned int* qkb = (unsigned int*)(ws + 524288);            // 8 MB bf16 pairs
    float* ctx        = (float*)(ws + 524288 + 8388608);         // 16 MB

    prep_kernel<<<dim3(512), dim3(256), 0, stream>>>(Wq, Wk, Wgate, M, Wgb);
    qk_kernel<<<dim3(B_N / 32), dim3(256), 0, stream>>>(center, M, qkb);
    attn_kernel<<<dim3(B_N / ROWS), dim3(256), 0, stream>>>(neigh, qkb, ppi, ctx);
    gate_kernel<<<dim3(B_N / 32), dim3(256), 0, stream>>>(center, ctx, Wgb, bgate, out);
}

// Round 15
// 259.285 us; speedup vs baseline: 1.2179x; 1.1018x over previous
//
#include <hip/hip_runtime.h>
#include <hip/hip_bf16.h>
#include <cstdint>

#define B_N 16384
#define KN 64
#define DN 256
#define AN 64
#define ROWS 4

typedef float f32x4 __attribute__((ext_vector_type(4)));
typedef float f32x2 __attribute__((ext_vector_type(2)));
typedef short s16x8 __attribute__((ext_vector_type(8)));

// pack two f32 -> one u32 of 2x bf16 (RTN); .x lands in low 16 bits
static __device__ inline unsigned int pk2(float a, float b) {
    __hip_bfloat162 h = __float22bfloat162_rn(make_float2(a, b));
    return *reinterpret_cast<unsigned int*>(&h);
}
static __device__ inline float bf_lo(unsigned int v) { return __uint_as_float(v << 16); }
static __device__ inline float bf_hi(unsigned int v) { return __uint_as_float(v & 0xFFFF0000u); }

// ---------------------------------------------------------------------------
// K0: M = Wq^T @ Wk (256x256 f32)  and  Wgb = bf16(Wgate) ([256 out][512 in])
// ---------------------------------------------------------------------------
__global__ __launch_bounds__(256) void prep_kernel(const float* __restrict__ Wq,
                                                   const float* __restrict__ Wk,
                                                   const float* __restrict__ Wgate,
                                                   float* __restrict__ M,
                                                   unsigned int* __restrict__ Wgb) {
    int blk = blockIdx.x;
    int t = threadIdx.x;
    if (blk < DN) {
        float acc = 0.f;
        #pragma unroll
        for (int a = 0; a < AN; ++a)
            acc += Wq[a * DN + blk] * Wk[a * DN + t];
        M[blk * DN + t] = acc;
    } else {
        int d = blk - DN;                    // 0..255 output row
        const float* src = Wgate + (size_t)d * (2 * DN);
        Wgb[(size_t)d * 256 + t] = pk2(src[2 * t], src[2 * t + 1]);
    }
}

// ---------------------------------------------------------------------------
// K0b: qk = center @ M, output bf16 pairs [B][128 words] (8 MB).
// M fully L2-resident here (no competing stream). R2-verified tile.
// ---------------------------------------------------------------------------
__global__ __launch_bounds__(256) void qk_kernel(const float* __restrict__ center,
                                                 const float* __restrict__ M,
                                                 unsigned int* __restrict__ qkb) {
    __shared__ float xs[32 * DN];            // 32 KB
    int r0 = blockIdx.x * 32;
    int tid = threadIdx.x;

    const float4* src = (const float4*)(center + (size_t)r0 * DN);
    float4* dst = (float4*)xs;
    #pragma unroll
    for (int i = 0; i < 8; ++i)
        dst[tid + 256 * i] = src[tid + 256 * i];
    __syncthreads();

    int ty = tid >> 5, tx = tid & 31;
    float acc[4][8];
    #pragma unroll
    for (int r = 0; r < 4; ++r)
        #pragma unroll
        for (int c = 0; c < 8; ++c) acc[r][c] = 0.f;

    for (int k4 = 0; k4 < DN; k4 += 4) {
        float4 xr[4];
        #pragma unroll
        for (int r = 0; r < 4; ++r)
            xr[r] = *(const float4*)(&xs[(ty * 4 + r) * DN + k4]);
        #pragma unroll
        for (int kk = 0; kk < 4; ++kk) {
            float4 ma = *(const float4*)(&M[(size_t)(k4 + kk) * DN + tx * 8]);
            float4 mb = *(const float4*)(&M[(size_t)(k4 + kk) * DN + tx * 8 + 4]);
            #pragma unroll
            for (int r = 0; r < 4; ++r) {
                float x = (&xr[r].x)[kk];
                acc[r][0] += x * ma.x; acc[r][1] += x * ma.y;
                acc[r][2] += x * ma.z; acc[r][3] += x * ma.w;
                acc[r][4] += x * mb.x; acc[r][5] += x * mb.y;
                acc[r][6] += x * mb.z; acc[r][7] += x * mb.w;
            }
        }
    }
    #pragma unroll
    for (int r = 0; r < 4; ++r) {
        size_t row = (size_t)(r0 + ty * 4 + r);
        uint4 o;
        o.x = pk2(acc[r][0], acc[r][1]);
        o.y = pk2(acc[r][2], acc[r][3]);
        o.z = pk2(acc[r][4], acc[r][5]);
        o.w = pk2(acc[r][6], acc[r][7]);
        *(uint4*)&qkb[row * 128 + tx * 4] = o;
    }
}

// ---------------------------------------------------------------------------
// K1: attention. R12-verified structure (255.5 us), single change: bound
// (256,3) -> 170-VGPR cap. rr[16]+temps ~110 live regs fit; if natural
// allocation was >170 this buys a 3rd resident block/CU (12 waves).
// 3 barriers/row: [guard] stage+prefetch [B1] logits [B2] softmax(all-wave,
// per-wave sattn, no barrier) + one-d-per-thread ctx.
// ---------------------------------------------------------------------------
__global__ __launch_bounds__(256, 3) void attn_kernel(const float* __restrict__ neigh,
                                                      const unsigned int* __restrict__ qkb,
                                                      const float* __restrict__ ppi,
                                                      float* __restrict__ ctx) {
    __shared__ unsigned int sn[KN * 128];    // 32 KB current tile (bf16 pairs)
    __shared__ unsigned int sqk[ROWS * 128]; //  2 KB q rows (bf16 pairs)
    __shared__ float slog[KN];               // 256 B logits
    __shared__ float sattn[4][KN];           //  1 KB per-wave attn copies

    const int tid = threadIdx.x;
    const int lane = tid & 63;
    const int wv = tid >> 6;
    const int b0 = blockIdx.x * ROWS;

    // issue row-0 tile prefetch (nontemporal: one-touch stream)
    f32x4 rr[16];
    {
        const f32x4* t4 = (const f32x4*)(neigh + (size_t)b0 * (KN * DN));
        #pragma unroll
        for (int i = 0; i < 16; ++i)
            rr[i] = __builtin_nontemporal_load(t4 + tid + 256 * i);
    }

    // qk rows -> LDS (512 words, one uint2 per thread)
    ((uint2*)sqk)[tid] = ((const uint2*)(qkb + (size_t)b0 * 128))[tid];

    // ppi rows -> registers (every wave keeps a copy; lane k holds ppi[k])
    float pv[ROWS];
    #pragma unroll
    for (int r = 0; r < ROWS; ++r) pv[r] = ppi[(size_t)(b0 + r) * KN + lane];

    #pragma unroll
    for (int r = 0; r < ROWS; ++r) {
        if (r > 0) __syncthreads();          // guard: prev row's ctx reads of sn done

        // staged regs -> sn (bf16 pairs)
        {
            uint2* dst = (uint2*)sn;
            #pragma unroll
            for (int i = 0; i < 16; ++i)
                dst[tid + 256 * i] = make_uint2(pk2(rr[i].x, rr[i].y), pk2(rr[i].z, rr[i].w));
        }
        // prefetch next row's tile (in flight during this row's compute)
        if (r < ROWS - 1) {
            const f32x4* n4 = (const f32x4*)(neigh + (size_t)(b0 + r + 1) * (KN * DN));
            #pragma unroll
            for (int i = 0; i < 16; ++i)
                rr[i] = __builtin_nontemporal_load(n4 + tid + 256 * i);
        }
        __syncthreads();                      // B1: sn (and for r=0: sqk) visible

        // logits: group g=tid>>2 owns k-row g; rotated d-walk (2-way banks)
        {
            const int g = tid >> 2, j = tid & 3;
            float acc = 0.f;
            #pragma unroll
            for (int m = 0; m < 32; ++m) {
                int s = (m + g) & 31;
                int p = j + 4 * s;            // pair index 0..127
                unsigned int nv = sn[g * 128 + p];
                unsigned int qv = sqk[r * 128 + p];
                acc += bf_lo(nv) * bf_lo(qv) + bf_hi(nv) * bf_hi(qv);
            }
            acc += __shfl_xor(acc, 1, 64);
            acc += __shfl_xor(acc, 2, 64);
            if (j == 0) slog[g] = acc;
        }
        __syncthreads();                      // B2: slog visible

        // softmax + ppi renorm: every wave redundantly; own sattn copy
        {
            float l = slog[lane] * 0.125f;    // scale = 64^-0.5
            float mx = l;
            #pragma unroll
            for (int off = 32; off >= 1; off >>= 1)
                mx = fmaxf(mx, __shfl_xor(mx, off, 64));
            float e = expf(l - mx);
            float se = e;
            #pragma unroll
            for (int off = 32; off >= 1; off >>= 1)
                se += __shfl_xor(se, off, 64);
            float t = (e / se) * pv[r];
            float st = t;
            #pragma unroll
            for (int off = 32; off >= 1; off >>= 1)
                st += __shfl_xor(st, off, 64);
            sattn[wv][lane] = t / (st + 1e-8f);
        }

        // ctx: one d per thread; adjacent lanes share each sn word
        // (same-address broadcast, free); fully-coalesced f32 store
        {
            const int w = tid >> 1;
            const int sh = (tid & 1) ? 0 : 16;
            float c = 0.f;
            #pragma unroll
            for (int k = 0; k < KN; ++k) {
                unsigned int nv = sn[k * 128 + w];
                float xv = __uint_as_float((nv << sh) & 0xFFFF0000u);
                c += sattn[wv][k] * xv;
            }
            __builtin_nontemporal_store(c, ctx + (size_t)(b0 + r) * DN + tid);
        }
    }
}

// ---------------------------------------------------------------------------
// K2: gate GEMM via MFMA bf16 + sigmoid blend (R7-verified, 32 rows/block).
// ---------------------------------------------------------------------------
__global__ __launch_bounds__(256) void gate_kernel(const float* __restrict__ center,
                                                   const float* __restrict__ ctxw,
                                                   const unsigned int* __restrict__ Wgb,
                                                   const float* __restrict__ bgate,
                                                   float* __restrict__ out) {
    __shared__ unsigned int xsb[32 * 260];   // 33.3 KB bf16 pairs: [cen 128 | ctx 128 | pad 4]
    const int r0 = blockIdx.x * 32;
    const int tid = threadIdx.x;

    const float4* c4 = (const float4*)(center + (size_t)r0 * DN);
    const float4* x4 = (const float4*)(ctxw + (size_t)r0 * DN);
    #pragma unroll
    for (int i = 0; i < 8; ++i) {
        int idx = tid + 256 * i;             // 0..2047
        int r = idx >> 6, c = idx & 63;
        float4 cv = c4[idx];
        float4 xv = x4[idx];
        *(uint2*)&xsb[r * 260 + 2 * c]       = make_uint2(pk2(cv.x, cv.y), pk2(cv.z, cv.w));
        *(uint2*)&xsb[r * 260 + 128 + 2 * c] = make_uint2(pk2(xv.x, xv.y), pk2(xv.z, xv.w));
    }
    __syncthreads();

    const int wave = tid >> 6, lane = tid & 63;
    const int l15 = lane & 15, lhi = lane >> 4;

    f32x4 acc[2][4];
    #pragma unroll
    for (int mt = 0; mt < 2; ++mt)
        #pragma unroll
        for (int nt = 0; nt < 4; ++nt)
            acc[mt][nt] = (f32x4){0.f, 0.f, 0.f, 0.f};

    #pragma unroll
    for (int ks = 0; ks < 16; ++ks) {        // K = 512 bf16, 32 per step
        s16x8 a0 = *(const s16x8*)&xsb[(l15)      * 260 + ks * 16 + lhi * 4];
        s16x8 a1 = *(const s16x8*)&xsb[(l15 + 16) * 260 + ks * 16 + lhi * 4];
        s16x8 b[4];
        #pragma unroll
        for (int nt = 0; nt < 4; ++nt) {
            int d = wave * 64 + nt * 16 + l15;
            b[nt] = *(const s16x8*)&Wgb[(size_t)d * 256 + ks * 16 + lhi * 4];
        }
        #pragma unroll
        for (int nt = 0; nt < 4; ++nt) {
            acc[0][nt] = __builtin_amdgcn_mfma_f32_16x16x32_bf16(a0, b[nt], acc[0][nt], 0, 0, 0);
            acc[1][nt] = __builtin_amdgcn_mfma_f32_16x16x32_bf16(a1, b[nt], acc[1][nt], 0, 0, 0);
        }
    }

    #pragma unroll
    for (int mt = 0; mt < 2; ++mt)
        #pragma unroll
        for (int nt = 0; nt < 4; ++nt) {
            int col = wave * 64 + nt * 16 + l15;
            float bg = bgate[col];
            #pragma unroll
            for (int reg = 0; reg < 4; ++reg) {
                int row = mt * 16 + lhi * 4 + reg;
                size_t gr = (size_t)(r0 + row);
                float z = acc[mt][nt][reg] + bg;
                float gt = 1.0f / (1.0f + expf(-z));
                float ce = center[gr * DN + col];   // f32, L2-warm
                float cx = ctxw[gr * DN + col];     // f32, L2-warm
                out[gr * DN + col] = gt * ce + (1.0f - gt) * cx;
            }
        }
}

// ---------------------------------------------------------------------------
extern "C" void kernel_launch(void* const* d_in, const int* in_sizes, int n_in,
                              void* d_out, int out_size, void* d_ws, size_t ws_size,
                              hipStream_t stream) {
    const float* center = (const float*)d_in[0];
    const float* neigh  = (const float*)d_in[1];
    const float* ppi    = (const float*)d_in[2];
    const float* Wq     = (const float*)d_in[3];
    const float* Wk     = (const float*)d_in[4];
    const float* Wgate  = (const float*)d_in[5];
    const float* bgate  = (const float*)d_in[6];
    float* out = (float*)d_out;

    char* ws = (char*)d_ws;
    float* M          = (float*)(ws);                            // 256 KB
    unsigned int* Wgb = (unsigned int*)(ws + 262144);            // 256 KB
    unsigned int* qkb = (unsigned int*)(ws + 524288);            // 8 MB bf16 pairs
    float* ctx        = (float*)(ws + 524288 + 8388608);         // 16 MB

    prep_kernel<<<dim3(512), dim3(256), 0, stream>>>(Wq, Wk, Wgate, M, Wgb);
    qk_kernel<<<dim3(B_N / 32), dim3(256), 0, stream>>>(center, M, qkb);
    attn_kernel<<<dim3(B_N / ROWS), dim3(256), 0, stream>>>(neigh, qkb, ppi, ctx);
    gate_kernel<<<dim3(B_N / 32), dim3(256), 0, stream>>>(center, ctx, Wgb, bgate, out);
}

// Round 16
// 255.238 us; speedup vs baseline: 1.2372x; 1.0159x over previous
//
#include <hip/hip_runtime.h>
#include <hip/hip_bf16.h>
#include <cstdint>

#define B_N 16384
#define KN 64
#define DN 256
#define AN 64
#define ROWS 4

typedef float f32x4 __attribute__((ext_vector_type(4)));
typedef short s16x8 __attribute__((ext_vector_type(8)));

// pack two f32 -> one u32 of 2x bf16 (RTN); .x lands in low 16 bits
static __device__ inline unsigned int pk2(float a, float b) {
    __hip_bfloat162 h = __float22bfloat162_rn(make_float2(a, b));
    return *reinterpret_cast<unsigned int*>(&h);
}
static __device__ inline float bf_lo(unsigned int v) { return __uint_as_float(v << 16); }
static __device__ inline float bf_hi(unsigned int v) { return __uint_as_float(v & 0xFFFF0000u); }

// ---------------------------------------------------------------------------
// K0: M = Wq^T @ Wk (256x256 f32)  and  Wgb = bf16(Wgate) ([256 out][512 in])
// ---------------------------------------------------------------------------
__global__ __launch_bounds__(256) void prep_kernel(const float* __restrict__ Wq,
                                                   const float* __restrict__ Wk,
                                                   const float* __restrict__ Wgate,
                                                   float* __restrict__ M,
                                                   unsigned int* __restrict__ Wgb) {
    int blk = blockIdx.x;
    int t = threadIdx.x;
    if (blk < DN) {
        float acc = 0.f;
        #pragma unroll
        for (int a = 0; a < AN; ++a)
            acc += Wq[a * DN + blk] * Wk[a * DN + t];
        M[blk * DN + t] = acc;
    } else {
        int d = blk - DN;                    // 0..255 output row
        const float* src = Wgate + (size_t)d * (2 * DN);
        Wgb[(size_t)d * 256 + t] = pk2(src[2 * t], src[2 * t + 1]);
    }
}

// ---------------------------------------------------------------------------
// K0b: qk = center @ M, output bf16 pairs [B][128 words] (8 MB).
// M fully L2-resident here (no competing stream). R2-verified tile.
// ---------------------------------------------------------------------------
__global__ __launch_bounds__(256) void qk_kernel(const float* __restrict__ center,
                                                 const float* __restrict__ M,
                                                 unsigned int* __restrict__ qkb) {
    __shared__ float xs[32 * DN];            // 32 KB
    int r0 = blockIdx.x * 32;
    int tid = threadIdx.x;

    const float4* src = (const float4*)(center + (size_t)r0 * DN);
    float4* dst = (float4*)xs;
    #pragma unroll
    for (int i = 0; i < 8; ++i)
        dst[tid + 256 * i] = src[tid + 256 * i];
    __syncthreads();

    int ty = tid >> 5, tx = tid & 31;
    float acc[4][8];
    #pragma unroll
    for (int r = 0; r < 4; ++r)
        #pragma unroll
        for (int c = 0; c < 8; ++c) acc[r][c] = 0.f;

    for (int k4 = 0; k4 < DN; k4 += 4) {
        float4 xr[4];
        #pragma unroll
        for (int r = 0; r < 4; ++r)
            xr[r] = *(const float4*)(&xs[(ty * 4 + r) * DN + k4]);
        #pragma unroll
        for (int kk = 0; kk < 4; ++kk) {
            float4 ma = *(const float4*)(&M[(size_t)(k4 + kk) * DN + tx * 8]);
            float4 mb = *(const float4*)(&M[(size_t)(k4 + kk) * DN + tx * 8 + 4]);
            #pragma unroll
            for (int r = 0; r < 4; ++r) {
                float x = (&xr[r].x)[kk];
                acc[r][0] += x * ma.x; acc[r][1] += x * ma.y;
                acc[r][2] += x * ma.z; acc[r][3] += x * ma.w;
                acc[r][4] += x * mb.x; acc[r][5] += x * mb.y;
                acc[r][6] += x * mb.z; acc[r][7] += x * mb.w;
            }
        }
    }
    #pragma unroll
    for (int r = 0; r < 4; ++r) {
        size_t row = (size_t)(r0 + ty * 4 + r);
        uint4 o;
        o.x = pk2(acc[r][0], acc[r][1]);
        o.y = pk2(acc[r][2], acc[r][3]);
        o.z = pk2(acc[r][4], acc[r][5]);
        o.w = pk2(acc[r][6], acc[r][7]);
        *(uint4*)&qkb[row * 128 + tx * 4] = o;
    }
}

// ---------------------------------------------------------------------------
// K1: attention. R12-verified structure + double-buffered sn (2x32 KB,
// compile-time r&1): stage(r+1) writes the opposite buffer from ctx(r)'s
// reads -> guard barrier deleted; 2 barriers/row. ~67.3 KB LDS -> same
// 2 blocks/CU regime; (256,2) bound; rr[16] deep prefetch kept.
// Safety: stage(r+2) reuses buf[r&1] only after iter r+1's two barriers.
// ---------------------------------------------------------------------------
__global__ __launch_bounds__(256, 2) void attn_kernel(const float* __restrict__ neigh,
                                                      const unsigned int* __restrict__ qkb,
                                                      const float* __restrict__ ppi,
                                                      float* __restrict__ ctx) {
    __shared__ unsigned int sn[2][KN * 128]; // 64 KB double-buffered tiles
    __shared__ unsigned int sqk[ROWS * 128]; //  2 KB q rows (bf16 pairs)
    __shared__ float slog[KN];               // 256 B logits
    __shared__ float sattn[4][KN];           //  1 KB per-wave attn copies

    const int tid = threadIdx.x;
    const int lane = tid & 63;
    const int wv = tid >> 6;
    const int b0 = blockIdx.x * ROWS;

    // issue row-0 tile prefetch (nontemporal: one-touch stream)
    f32x4 rr[16];
    {
        const f32x4* t4 = (const f32x4*)(neigh + (size_t)b0 * (KN * DN));
        #pragma unroll
        for (int i = 0; i < 16; ++i)
            rr[i] = __builtin_nontemporal_load(t4 + tid + 256 * i);
    }

    // qk rows -> LDS (512 words, one uint2 per thread)
    ((uint2*)sqk)[tid] = ((const uint2*)(qkb + (size_t)b0 * 128))[tid];

    // ppi rows -> registers (every wave keeps a copy; lane k holds ppi[k])
    float pv[ROWS];
    #pragma unroll
    for (int r = 0; r < ROWS; ++r) pv[r] = ppi[(size_t)(b0 + r) * KN + lane];

    #pragma unroll
    for (int r = 0; r < ROWS; ++r) {
        unsigned int* snb = sn[r & 1];        // compile-time (full unroll)

        // staged regs -> snb (bf16 pairs); no guard barrier needed (dbuf)
        {
            uint2* dst = (uint2*)snb;
            #pragma unroll
            for (int i = 0; i < 16; ++i)
                dst[tid + 256 * i] = make_uint2(pk2(rr[i].x, rr[i].y), pk2(rr[i].z, rr[i].w));
        }
        // prefetch next row's tile (in flight during this row's compute)
        if (r < ROWS - 1) {
            const f32x4* n4 = (const f32x4*)(neigh + (size_t)(b0 + r + 1) * (KN * DN));
            #pragma unroll
            for (int i = 0; i < 16; ++i)
                rr[i] = __builtin_nontemporal_load(n4 + tid + 256 * i);
        }
        __syncthreads();                      // B1: snb (and for r=0: sqk) visible

        // logits: group g=tid>>2 owns k-row g; rotated d-walk (2-way banks)
        {
            const int g = tid >> 2, j = tid & 3;
            float acc = 0.f;
            #pragma unroll
            for (int m = 0; m < 32; ++m) {
                int s = (m + g) & 31;
                int p = j + 4 * s;            // pair index 0..127
                unsigned int nv = snb[g * 128 + p];
                unsigned int qv = sqk[r * 128 + p];
                acc += bf_lo(nv) * bf_lo(qv) + bf_hi(nv) * bf_hi(qv);
            }
            acc += __shfl_xor(acc, 1, 64);
            acc += __shfl_xor(acc, 2, 64);
            if (j == 0) slog[g] = acc;
        }
        __syncthreads();                      // B2: slog visible

        // softmax + ppi renorm: every wave redundantly; own sattn copy
        {
            float l = slog[lane] * 0.125f;    // scale = 64^-0.5
            float mx = l;
            #pragma unroll
            for (int off = 32; off >= 1; off >>= 1)
                mx = fmaxf(mx, __shfl_xor(mx, off, 64));
            float e = expf(l - mx);
            float se = e;
            #pragma unroll
            for (int off = 32; off >= 1; off >>= 1)
                se += __shfl_xor(se, off, 64);
            float t = (e / se) * pv[r];
            float st = t;
            #pragma unroll
            for (int off = 32; off >= 1; off >>= 1)
                st += __shfl_xor(st, off, 64);
            sattn[wv][lane] = t / (st + 1e-8f);
        }

        // ctx: one d per thread; adjacent lanes share each snb word
        // (same-address broadcast, free); fully-coalesced f32 store
        {
            const int w = tid >> 1;
            const int sh = (tid & 1) ? 0 : 16;
            float c = 0.f;
            #pragma unroll
            for (int k = 0; k < KN; ++k) {
                unsigned int nv = snb[k * 128 + w];
                float xv = __uint_as_float((nv << sh) & 0xFFFF0000u);
                c += sattn[wv][k] * xv;
            }
            __builtin_nontemporal_store(c, ctx + (size_t)(b0 + r) * DN + tid);
        }
    }
}

// ---------------------------------------------------------------------------
// K2: gate GEMM via MFMA bf16 + sigmoid blend (R7-verified, 32 rows/block).
// ---------------------------------------------------------------------------
__global__ __launch_bounds__(256) void gate_kernel(const float* __restrict__ center,
                                                   const float* __restrict__ ctxw,
                                                   const unsigned int* __restrict__ Wgb,
                                                   const float* __restrict__ bgate,
                                                   float* __restrict__ out) {
    __shared__ unsigned int xsb[32 * 260];   // 33.3 KB bf16 pairs: [cen 128 | ctx 128 | pad 4]
    const int r0 = blockIdx.x * 32;
    const int tid = threadIdx.x;

    const float4* c4 = (const float4*)(center + (size_t)r0 * DN);
    const float4* x4 = (const float4*)(ctxw + (size_t)r0 * DN);
    #pragma unroll
    for (int i = 0; i < 8; ++i) {
        int idx = tid + 256 * i;             // 0..2047
        int r = idx >> 6, c = idx & 63;
        float4 cv = c4[idx];
        float4 xv = x4[idx];
        *(uint2*)&xsb[r * 260 + 2 * c]       = make_uint2(pk2(cv.x, cv.y), pk2(cv.z, cv.w));
        *(uint2*)&xsb[r * 260 + 128 + 2 * c] = make_uint2(pk2(xv.x, xv.y), pk2(xv.z, xv.w));
    }
    __syncthreads();

    const int wave = tid >> 6, lane = tid & 63;
    const int l15 = lane & 15, lhi = lane >> 4;

    f32x4 acc[2][4];
    #pragma unroll
    for (int mt = 0; mt < 2; ++mt)
        #pragma unroll
        for (int nt = 0; nt < 4; ++nt)
            acc[mt][nt] = (f32x4){0.f, 0.f, 0.f, 0.f};

    #pragma unroll
    for (int ks = 0; ks < 16; ++ks) {        // K = 512 bf16, 32 per step
        s16x8 a0 = *(const s16x8*)&xsb[(l15)      * 260 + ks * 16 + lhi * 4];
        s16x8 a1 = *(const s16x8*)&xsb[(l15 + 16) * 260 + ks * 16 + lhi * 4];
        s16x8 b[4];
        #pragma unroll
        for (int nt = 0; nt < 4; ++nt) {
            int d = wave * 64 + nt * 16 + l15;
            b[nt] = *(const s16x8*)&Wgb[(size_t)d * 256 + ks * 16 + lhi * 4];
        }
        #pragma unroll
        for (int nt = 0; nt < 4; ++nt) {
            acc[0][nt] = __builtin_amdgcn_mfma_f32_16x16x32_bf16(a0, b[nt], acc[0][nt], 0, 0, 0);
            acc[1][nt] = __builtin_amdgcn_mfma_f32_16x16x32_bf16(a1, b[nt], acc[1][nt], 0, 0, 0);
        }
    }

    #pragma unroll
    for (int mt = 0; mt < 2; ++mt)
        #pragma unroll
        for (int nt = 0; nt < 4; ++nt) {
            int col = wave * 64 + nt * 16 + l15;
            float bg = bgate[col];
            #pragma unroll
            for (int reg = 0; reg < 4; ++reg) {
                int row = mt * 16 + lhi * 4 + reg;
                size_t gr = (size_t)(r0 + row);
                float z = acc[mt][nt][reg] + bg;
                float gt = 1.0f / (1.0f + expf(-z));
                float ce = center[gr * DN + col];   // f32, L2-warm
                float cx = ctxw[gr * DN + col];     // f32, L2-warm
                out[gr * DN + col] = gt * ce + (1.0f - gt) * cx;
            }
        }
}

// ---------------------------------------------------------------------------
extern "C" void kernel_launch(void* const* d_in, const int* in_sizes, int n_in,
                              void* d_out, int out_size, void* d_ws, size_t ws_size,
                              hipStream_t stream) {
    const float* center = (const float*)d_in[0];
    const float* neigh  = (const float*)d_in[1];
    const float* ppi    = (const float*)d_in[2];
    const float* Wq     = (const float*)d_in[3];
    const float* Wk     = (const float*)d_in[4];
    const float* Wgate  = (const float*)d_in[5];
    const float* bgate  = (const float*)d_in[6];
    float* out = (float*)d_out;

    char* ws = (char*)d_ws;
    float* M          = (float*)(ws);                            // 256 KB
    unsigned int* Wgb = (unsigned int*)(ws + 262144);            // 256 KB
    unsigned int* qkb = (unsigned int*)(ws + 524288);            // 8 MB bf16 pairs
    float* ctx        = (float*)(ws + 524288 + 8388608);         // 16 MB

    prep_kernel<<<dim3(512), dim3(256), 0, stream>>>(Wq, Wk, Wgate, M, Wgb);
    qk_kernel<<<dim3(B_N / 32), dim3(256), 0, stream>>>(center, M, qkb);
    attn_kernel<<<dim3(B_N / ROWS), dim3(256), 0, stream>>>(neigh, qkb, ppi, ctx);
    gate_kernel<<<dim3(B_N / 32), dim3(256), 0, stream>>>(center, ctx, Wgb, bgate, out);
}